// Round 4
// baseline (355.621 us; speedup 1.0000x reference)
//
#include <hip/hip_runtime.h>
#include <hip/hip_bf16.h>

// BGraphAttentionLayer: fused GAT layer, never materializes the 8192^2 attention.
// hp1 = E @ (Wh2/Z2), hp2 = E^T @ (Wh1/Z1), E = adj>0 ? exp(lrelu(s1_i+s2_j)) : 0.
// Key insight: adj enters only via sign -> one 256MB sweep builds an 8MB bitmask
// + Z1/Z2; the two MFMA sweeps recompute E from (mask, s1, s2) with ~zero HBM.

#define N 8192
#define FIN 256
#define FOUT 64

typedef float f32x4 __attribute__((ext_vector_type(4)));
typedef short s16x8 __attribute__((ext_vector_type(8)));
typedef unsigned short u16;
typedef unsigned long long u64;

__device__ __forceinline__ u16 f2bf(float x) {
  unsigned u = __builtin_bit_cast(unsigned, x);
  return (u16)((u + 0x7FFFu + ((u >> 16) & 1u)) >> 16);  // RTNE
}
__device__ __forceinline__ u16 f2bf_t(float x) {  // truncating (cheap)
  return (u16)(__builtin_bit_cast(unsigned, x) >> 16);
}
__device__ __forceinline__ float lrexp(float x) {
  return __expf(fmaxf(x, 0.2f * x));  // exp(leaky_relu(x, 0.2))
}

// ---------------- K1: Wh1/Wh2 (transposed, f32) + s1/s2 ----------------
__global__ __launch_bounds__(256) void k_prep(
    const float* __restrict__ h1, const float* __restrict__ h2,
    const float* __restrict__ W1, const float* __restrict__ W2,
    const float* __restrict__ a,
    float* __restrict__ Wh1T, float* __restrict__ Wh2T,
    float* __restrict__ s1, float* __restrict__ s2) {
  __shared__ float hbuf[16][FIN];
  const int t = threadIdx.x;
  const int r0 = blockIdx.x * 16;
  const int f = t & 63, q = t >> 6;
  const int lrow = t >> 4, lc0 = (t & 15) * 16;
  for (int mat = 0; mat < 2; ++mat) {
    const float* h = mat ? h2 : h1;
    const float* W = mat ? W2 : W1;
    float* WhT = mat ? Wh2T : Wh1T;
    float* so = mat ? s2 : s1;
    const float av = a[mat * FOUT + f];
    __syncthreads();
    const float* src = h + (size_t)(r0 + lrow) * FIN + lc0;
#pragma unroll
    for (int u = 0; u < 4; ++u)
      *(f32x4*)&hbuf[lrow][lc0 + u * 4] = *(const f32x4*)(src + u * 4);
    __syncthreads();
    float acc[4] = {0.f, 0.f, 0.f, 0.f};
    for (int k = 0; k < FIN; ++k) {
      float wv = W[k * FOUT + f];
#pragma unroll
      for (int rg = 0; rg < 4; ++rg)
        acc[rg] = fmaf(hbuf[rg * 4 + q][k], wv, acc[rg]);
    }
#pragma unroll
    for (int rg = 0; rg < 4; ++rg) {
      int r = r0 + rg * 4 + q;
      WhT[(size_t)f * N + r] = acc[rg];
      float sp = acc[rg] * av;
#pragma unroll
      for (int m = 1; m < 64; m <<= 1) sp += __shfl_xor(sp, m, 64);
      if (f == 0) so[r] = sp;
    }
  }
}

// ------- K2: one adj sweep -> Z1 (row sums), Z2 (col sums), bitmask -------
// grid (2 j-stripes of 4096, 256 i-chunks of 32); thread owns 16 consecutive j.
__global__ __launch_bounds__(256) void k_statsmask(
    const float* __restrict__ adj, const float* __restrict__ s1,
    const float* __restrict__ s2, float* __restrict__ Z1,
    float* __restrict__ Z2, u16* __restrict__ mask) {
  const int t = threadIdx.x;
  const int c0 = blockIdx.x * 4096 + t * 16;
  const int r0 = blockIdx.y * 32;
  const int wv = t >> 6, lane = t & 63;
  __shared__ float rowpart[4][32];
  float s2v[16];
#pragma unroll
  for (int e = 0; e < 16; e += 4)
    *(f32x4*)&s2v[e] = *(const f32x4*)(s2 + c0 + e);
  f32x4 ca[4];
#pragma unroll
  for (int q = 0; q < 4; ++q) ca[q] = f32x4{0.f, 0.f, 0.f, 0.f};

  f32x4 va[4], vb[4];
#pragma unroll
  for (int q = 0; q < 4; ++q)
    va[q] = *(const f32x4*)(adj + (size_t)r0 * N + c0 + q * 4);

  auto loadrow = [&](int r, f32x4 (&v)[4]) {
#pragma unroll
    for (int q = 0; q < 4; ++q)
      v[q] = *(const f32x4*)(adj + (size_t)(r0 + r) * N + c0 + q * 4);
  };
  auto proc = [&](int r, f32x4 (&v)[4]) {
    const float s1v = s1[r0 + r];
    unsigned m = 0;
    float rs = 0.f;
#pragma unroll
    for (int q = 0; q < 4; ++q)
#pragma unroll
      for (int c = 0; c < 4; ++c) {
        const int e = q * 4 + c;
        float ev = lrexp(s1v + s2v[e]);
        const bool on = v[q][c] > 0.f;
        ev = on ? ev : 0.f;
        m |= on ? (1u << e) : 0u;
        ca[q][c] += ev;
        rs += ev;
      }
    mask[(size_t)(r0 + r) * 512 + (c0 >> 4)] = (u16)m;
#pragma unroll
    for (int sh = 1; sh < 64; sh <<= 1) rs += __shfl_xor(rs, sh, 64);
    if (lane == 0) rowpart[wv][r] = rs;
  };

  for (int r = 0; r < 32; r += 2) {
    loadrow(r + 1, vb);
    proc(r, va);
    if (r + 2 < 32) loadrow(r + 2, va);
    proc(r + 1, vb);
  }
  __syncthreads();
  if (t < 32) {
    float s = rowpart[0][t] + rowpart[1][t] + rowpart[2][t] + rowpart[3][t];
    atomicAdd(&Z1[r0 + t], s);
  }
#pragma unroll
  for (int q = 0; q < 4; ++q)
#pragma unroll
    for (int c = 0; c < 4; ++c) atomicAdd(&Z2[c0 + q * 4 + c], ca[q][c]);
}

// ---------------- K3: V{1,2}T = (Wh/Z)^T in bf16 ----------------
__global__ __launch_bounds__(256) void k_buildv(
    const float* __restrict__ Wh1T, const float* __restrict__ Wh2T,
    const float* __restrict__ Z1, const float* __restrict__ Z2,
    u16* __restrict__ V1T, u16* __restrict__ V2T) {
  const int mat = blockIdx.y;
  const float* WhT = mat ? Wh2T : Wh1T;
  const float* Z = mat ? Z2 : Z1;
  u16* VT = mat ? V2T : V1T;
  const int idx = (blockIdx.x * 256 + threadIdx.x) * 4;
  const int i = idx & (N - 1);
  f32x4 wh = *(const f32x4*)(WhT + idx);
  f32x4 z = *(const f32x4*)(Z + i);
  unsigned lo = (unsigned)f2bf(wh.x / z.x) | ((unsigned)f2bf(wh.y / z.y) << 16);
  unsigned hi = (unsigned)f2bf(wh.z / z.z) | ((unsigned)f2bf(wh.w / z.w) << 16);
  uint2 uv; uv.x = lo; uv.y = hi;
  *(uint2*)(VT + idx) = uv;
}

// -------- K4a: hp1 += E @ V2. Barrier-free, LDS-free, mask-driven. --------
// grid (64 i-chunks of 128, 16 j-strips of 512). Wave owns 32 rows.
__global__ __launch_bounds__(256) void k_hp1(
    const u16* __restrict__ maskp, const float* __restrict__ s1g,
    const float* __restrict__ s2g, const u16* __restrict__ V2T,
    float* __restrict__ hp1) {
  const int t = threadIdx.x, w = t >> 6, lane = t & 63;
  const int l15 = lane & 15, l4 = lane >> 4;
  const int sh0 = l4 * 8;
  const int i0 = blockIdx.x * 128 + w * 32;
  const int jbase = blockIdx.y * 512;
  const u64* mrow0 = (const u64*)maskp + (size_t)(i0 + l15) * 128;
  const u64* mrow1 = mrow0 + 16 * 128;
  const float s1v0 = s1g[i0 + l15];
  const float s1v1 = s1g[i0 + 16 + l15];
  f32x4 acc[2][4];
#pragma unroll
  for (int mt = 0; mt < 2; ++mt)
#pragma unroll
    for (int nt = 0; nt < 4; ++nt) acc[mt][nt] = f32x4{0.f, 0.f, 0.f, 0.f};

#pragma unroll 2
  for (int js = 0; js < 8; ++js) {
    const int j0s = jbase + js * 64;
    const u64 m0 = mrow0[j0s >> 6];
    const u64 m1 = mrow1[j0s >> 6];
    f32x4 s2q[4];  // [kk*2+h]: s2[j0s + kk*32 + sh0 + h*4 ..]
#pragma unroll
    for (int kk = 0; kk < 2; ++kk)
#pragma unroll
      for (int h = 0; h < 2; ++h)
        s2q[kk * 2 + h] = *(const f32x4*)(s2g + j0s + kk * 32 + sh0 + h * 4);
    s16x8 bf[2][4];
#pragma unroll
    for (int kk = 0; kk < 2; ++kk)
#pragma unroll
      for (int nt = 0; nt < 4; ++nt)
        bf[kk][nt] = *(const s16x8*)(V2T + (size_t)(nt * 16 + l15) * N + j0s +
                                     kk * 32 + sh0);
    s16x8 afr[2][2];  // [mt][kk]
#pragma unroll
    for (int kk = 0; kk < 2; ++kk) {
      const unsigned b0 = (unsigned)(kk ? (m0 >> 32) : m0);
      const unsigned b1 = (unsigned)(kk ? (m1 >> 32) : m1);
#pragma unroll
      for (int e = 0; e < 8; ++e) {
        const float s2e = s2q[kk * 2 + (e >> 2)][e & 3];
        float e0 = lrexp(s1v0 + s2e);
        float e1 = lrexp(s1v1 + s2e);
        e0 = ((b0 >> (sh0 + e)) & 1u) ? e0 : 0.f;
        e1 = ((b1 >> (sh0 + e)) & 1u) ? e1 : 0.f;
        afr[0][kk][e] = (short)f2bf_t(e0);
        afr[1][kk][e] = (short)f2bf_t(e1);
      }
    }
#pragma unroll
    for (int nt = 0; nt < 4; ++nt) {
      acc[0][nt] = __builtin_amdgcn_mfma_f32_16x16x32_bf16(afr[0][0], bf[0][nt],
                                                           acc[0][nt], 0, 0, 0);
      acc[0][nt] = __builtin_amdgcn_mfma_f32_16x16x32_bf16(afr[0][1], bf[1][nt],
                                                           acc[0][nt], 0, 0, 0);
      acc[1][nt] = __builtin_amdgcn_mfma_f32_16x16x32_bf16(afr[1][0], bf[0][nt],
                                                           acc[1][nt], 0, 0, 0);
      acc[1][nt] = __builtin_amdgcn_mfma_f32_16x16x32_bf16(afr[1][1], bf[1][nt],
                                                           acc[1][nt], 0, 0, 0);
    }
  }
#pragma unroll
  for (int mt = 0; mt < 2; ++mt)
#pragma unroll
    for (int nt = 0; nt < 4; ++nt)
#pragma unroll
      for (int r = 0; r < 4; ++r)
        atomicAdd(&hp1[(size_t)(i0 + mt * 16 + l4 * 4 + r) * 64 + nt * 16 + l15],
                  acc[mt][nt][r]);
}

// -------- K4b: hp2 += E^T @ V1. Barrier-free, LDS-free, mask-driven. --------
// grid (64 j-chunks of 128, 16 i-strips of 512 = 8 tiles of 64). Wave owns 32 j.
__global__ __launch_bounds__(256) void k_hp2(
    const u16* __restrict__ maskp, const float* __restrict__ s1g,
    const float* __restrict__ s2g, const u16* __restrict__ V1T,
    float* __restrict__ hp2) {
  const int t = threadIdx.x, w = t >> 6, lane = t & 63;
  const int l15 = lane & 15, l4 = lane >> 4;
  const int sh0 = l4 * 8;
  const int j0w = blockIdx.x * 128 + w * 32;
  const int ibase = blockIdx.y * 512;
  const float s2vA = s2g[j0w + l15];
  const float s2vB = s2g[j0w + 16 + l15];
  // one u32 of the mask row covers both mt sub-cols (j0w%32==0)
  const unsigned* mask32 = (const unsigned*)maskp;
  const int wsel = j0w >> 5;  // u32 index within a 256-word row
  f32x4 acc[2][4];
#pragma unroll
  for (int mt = 0; mt < 2; ++mt)
#pragma unroll
    for (int nt = 0; nt < 4; ++nt) acc[mt][nt] = f32x4{0.f, 0.f, 0.f, 0.f};

#pragma unroll 2
  for (int tile = 0; tile < 8; ++tile) {
    const int it0 = ibase + tile * 64;
    f32x4 s1q[4];
#pragma unroll
    for (int kk = 0; kk < 2; ++kk)
#pragma unroll
      for (int h = 0; h < 2; ++h)
        s1q[kk * 2 + h] = *(const f32x4*)(s1g + it0 + kk * 32 + sh0 + h * 4);
    unsigned mw[2][8];
#pragma unroll
    for (int kk = 0; kk < 2; ++kk)
#pragma unroll
      for (int e = 0; e < 8; ++e)
        mw[kk][e] = mask32[(size_t)(it0 + kk * 32 + sh0 + e) * 256 + wsel];
    s16x8 bf[2][4];
#pragma unroll
    for (int kk = 0; kk < 2; ++kk)
#pragma unroll
      for (int nt = 0; nt < 4; ++nt)
        bf[kk][nt] = *(const s16x8*)(V1T + (size_t)(nt * 16 + l15) * N + it0 +
                                     kk * 32 + sh0);
    s16x8 aA[2], aB[2];  // [kk] for mt=0 / mt=1
#pragma unroll
    for (int kk = 0; kk < 2; ++kk)
#pragma unroll
      for (int e = 0; e < 8; ++e) {
        const float s1v = s1q[kk * 2 + (e >> 2)][e & 3];
        float eA = lrexp(s1v + s2vA);
        float eB = lrexp(s1v + s2vB);
        const unsigned mwv = mw[kk][e];
        eA = ((mwv >> l15) & 1u) ? eA : 0.f;
        eB = ((mwv >> (16 + l15)) & 1u) ? eB : 0.f;
        aA[kk][e] = (short)f2bf_t(eA);
        aB[kk][e] = (short)f2bf_t(eB);
      }
#pragma unroll
    for (int nt = 0; nt < 4; ++nt) {
      acc[0][nt] = __builtin_amdgcn_mfma_f32_16x16x32_bf16(aA[0], bf[0][nt],
                                                           acc[0][nt], 0, 0, 0);
      acc[0][nt] = __builtin_amdgcn_mfma_f32_16x16x32_bf16(aA[1], bf[1][nt],
                                                           acc[0][nt], 0, 0, 0);
      acc[1][nt] = __builtin_amdgcn_mfma_f32_16x16x32_bf16(aB[0], bf[0][nt],
                                                           acc[1][nt], 0, 0, 0);
      acc[1][nt] = __builtin_amdgcn_mfma_f32_16x16x32_bf16(aB[1], bf[1][nt],
                                                           acc[1][nt], 0, 0, 0);
    }
  }
#pragma unroll
  for (int mt = 0; mt < 2; ++mt)
#pragma unroll
    for (int nt = 0; nt < 4; ++nt)
#pragma unroll
      for (int r = 0; r < 4; ++r)
        atomicAdd(
            &hp2[(size_t)(j0w + mt * 16 + l4 * 4 + r) * 64 + nt * 16 + l15],
            acc[mt][nt][r]);
}

// ---------------- K5: ELU epilogue for both outputs ----------------
__global__ __launch_bounds__(256) void k_red(const float* __restrict__ hp1,
                                             const float* __restrict__ hp2,
                                             float* __restrict__ out) {
  const size_t idx = ((size_t)blockIdx.x * 256 + threadIdx.x) * 4;
  f32x4 v1 = *(const f32x4*)(hp1 + idx);
  f32x4 v2 = *(const f32x4*)(hp2 + idx);
  f32x4 o1, o2;
#pragma unroll
  for (int c = 0; c < 4; ++c) {
    o1[c] = v1[c] > 0.f ? v1[c] : expm1f(v1[c]);
    o2[c] = v2[c] > 0.f ? v2[c] : expm1f(v2[c]);
  }
  *(f32x4*)(out + idx) = o1;
  *(f32x4*)(out + (size_t)N * FOUT + idx) = o2;
}

extern "C" void kernel_launch(void* const* d_in, const int* in_sizes, int n_in,
                              void* d_out, int out_size, void* d_ws,
                              size_t ws_size, hipStream_t stream) {
  const float* h1 = (const float*)d_in[0];
  const float* h2 = (const float*)d_in[1];
  const float* adj = (const float*)d_in[2];
  const float* W1 = (const float*)d_in[3];
  const float* W2 = (const float*)d_in[4];
  const float* a = (const float*)d_in[5];

  float* ws = (float*)d_ws;
  // float-offset workspace layout (~19 MB total)
  float* s1 = ws + 0;
  float* s2 = ws + 8192;
  float* Z1 = ws + 16384;
  float* Z2 = ws + 24576;
  float* Wh1T = ws + 32768;               // [64][8192] f32
  float* Wh2T = ws + 557056;
  u16* V1T = (u16*)(ws + 1081344);        // [64][8192] bf16
  u16* V2T = V1T + 524288;
  u16* mask = (u16*)(ws + 1605632);       // [8192][512] u16 = 8 MB bitmask
  float* hp1 = ws + 3702784;              // [8192][64] f32
  float* hp2 = ws + 4227072;              // ends 4751360 floats

  hipMemsetAsync(Z1, 0, 2 * 8192 * sizeof(float), stream);               // Z1+Z2
  hipMemsetAsync(hp1, 0, 2 * (size_t)N * FOUT * sizeof(float), stream);  // hp1+hp2

  k_prep<<<512, 256, 0, stream>>>(h1, h2, W1, W2, a, Wh1T, Wh2T, s1, s2);
  k_statsmask<<<dim3(2, 256), 256, 0, stream>>>(adj, s1, s2, Z1, Z2, mask);
  k_buildv<<<dim3(512, 2), 256, 0, stream>>>(Wh1T, Wh2T, Z1, Z2, V1T, V2T);
  k_hp1<<<dim3(64, 16), 256, 0, stream>>>(mask, s1, s2, V2T, hp1);
  k_hp2<<<dim3(64, 16), 256, 0, stream>>>(mask, s1, s2, V1T, hp2);
  k_red<<<512, 256, 0, stream>>>(hp1, hp2, (float*)d_out);
}